// Round 2
// baseline (250.970 us; speedup 1.0000x reference)
//
#include <hip/hip_runtime.h>

// Dynamic grouped conv, factorized: the dynamic 3x3 kernel is broadcast across
// the 8 input channels of each group (reshape(b,64,1,3,3) + broadcast), so
//   out[b,oc] = conv3x3( S[b,g], w[b,oc] ),  S[b,g] = sum of the group's 8 chans.
//
// One fused kernel, block = (b, g, 32x64 tile):
//   - threads 0..71 compute w[oc,tap] = leaky_relu(rep[b,:] . W[(g*8+oc)*9+tap,:])
//   - barrier
//   - phase 1: group-sum into LDS tile. Layout: s[row][c] with row stride 68,
//     c in [0,64) = x cols gx0..gx0+63 (float4 loads + aligned b128 stores),
//     c==64 = right halo (x col gx0+64), c==66 = left halo (x col gx0-1).
//     Reflection pad folded into index math; interior cols never reflect.
//   - barrier
//   - phase 2: 4 pixels/thread, 3x6 register window, 8 ocs, float4 stores.

#define TH 32
#define TW 64
#define LDSW 68   // row stride in floats; rows 16B-aligned

__device__ __forceinline__ int reflect1(int i, int n) {
  if (i < 0) i = -i;
  if (i >= n) i = 2 * n - 2 - i;
  return i;
}

__global__ __launch_bounds__(256) void dynconv_kernel(
    const float* __restrict__ x,     // [8,64,256,256] fp32
    const float* __restrict__ rep,   // [8,32]
    const float* __restrict__ W,     // [576,32]
    float* __restrict__ out) {       // [8,64,256,256] fp32
  const int tid = threadIdx.x;
  const int tx = blockIdx.x & 3;          // 4 tiles of 64 along x
  const int ty = (blockIdx.x >> 2) & 7;   // 8 tiles of 32 along y
  const int g  = (blockIdx.x >> 5) & 7;   // group
  const int b  = blockIdx.x >> 8;         // batch

  __shared__ float s[(TH + 2) * LDSW];
  __shared__ float wl[72];                // 8 ocs x 9 taps

  // ---- dynamic weights for this (b, g) ----
  if (tid < 72) {
    const int row = g * 72 + tid;         // (g*8 + oc)*9 + tap
    const float* wr = W + (size_t)row * 32;
    const float* rb = rep + b * 32;
    float acc = 0.f;
#pragma unroll
    for (int j = 0; j < 32; ++j) acc += rb[j] * wr[j];
    wl[tid] = (acc > 0.f) ? acc : 0.1f * acc;
  }
  __syncthreads();

  // ---- phase 1: group-sum of 8 channels into LDS ----
  const int gx0 = tx * TW, gy0 = ty * TH;
  const float* xg = x + ((size_t)(b * 64 + g * 8)) * 65536;
  const float4* xg4 = (const float4*)xg;

  // interior: 34 rows x 16 float4 segments (x cols gx0 .. gx0+63, never reflect)
  for (int t = tid; t < 34 * 16; t += 256) {
    const int row = t >> 4, seg = t & 15;
    const int yy = reflect1(gy0 + row - 1, 256);
    const float4* p = xg4 + (size_t)yy * 64 + (gx0 >> 2) + seg;
    float4 a; a.x = 0.f; a.y = 0.f; a.z = 0.f; a.w = 0.f;
#pragma unroll
    for (int c = 0; c < 8; ++c) {
      float4 v = p[(size_t)c * 16384];
      a.x += v.x; a.y += v.y; a.z += v.z; a.w += v.w;
    }
    *(float4*)&s[row * LDSW + seg * 4] = a;   // 16B-aligned LDS store
  }
  // halo: 34 rows x {left, right} columns (scalar, with reflect)
  if (tid < 68) {
    const int row = tid >> 1, side = tid & 1;
    const int scol = side ? 64 : 66;                  // s col for right / left halo
    const int yy = reflect1(gy0 + row - 1, 256);
    const int xx = reflect1(gx0 + (side ? 64 : -1), 256);
    const float* p = xg + (size_t)yy * 256 + xx;
    float a = 0.f;
#pragma unroll
    for (int c = 0; c < 8; ++c) a += p[(size_t)c * 65536];
    s[row * LDSW + scol] = a;
  }
  __syncthreads();

  // ---- phase 2: 4 pixels/thread, 8 ocs ----
  const int cs = (tid & 15) * 4;   // output column segment start within tile
  const int r0 = tid >> 4;

  for (int rr = r0; rr < TH; rr += 16) {
    // win[dy][dx] = S[y-1+dy][gx0 + cs-1+dx]
    float win[3][6];
#pragma unroll
    for (int dy = 0; dy < 3; ++dy) {
#pragma unroll
      for (int dx = 0; dx < 6; ++dx) {
        const int col = cs - 1 + dx;              // x col offset within tile, -1..64
        const int scol = (col < 0) ? 66 : col;    // left halo lives at s col 66
        win[dy][dx] = s[(rr + dy) * LDSW + scol];
      }
    }

    const int y = gy0 + rr;
    float* ob = out + (((size_t)(b * 64 + g * 8) * 256 + y) * 256 + gx0 + cs);

#pragma unroll
    for (int oc = 0; oc < 8; ++oc) {
      const float* w = &wl[oc * 9];
      const float w00 = w[0], w01 = w[1], w02 = w[2];
      const float w10 = w[3], w11 = w[4], w12 = w[5];
      const float w20 = w[6], w21 = w[7], w22 = w[8];
      float4 o;
      o.x = w00 * win[0][0] + w01 * win[0][1] + w02 * win[0][2]
          + w10 * win[1][0] + w11 * win[1][1] + w12 * win[1][2]
          + w20 * win[2][0] + w21 * win[2][1] + w22 * win[2][2];
      o.y = w00 * win[0][1] + w01 * win[0][2] + w02 * win[0][3]
          + w10 * win[1][1] + w11 * win[1][2] + w12 * win[1][3]
          + w20 * win[2][1] + w21 * win[2][2] + w22 * win[2][3];
      o.z = w00 * win[0][2] + w01 * win[0][3] + w02 * win[0][4]
          + w10 * win[1][2] + w11 * win[1][3] + w12 * win[1][4]
          + w20 * win[2][2] + w21 * win[2][3] + w22 * win[2][4];
      o.w = w00 * win[0][3] + w01 * win[0][4] + w02 * win[0][5]
          + w10 * win[1][3] + w11 * win[1][4] + w12 * win[1][5]
          + w20 * win[2][3] + w21 * win[2][4] + w22 * win[2][5];
      *(float4*)(ob + (size_t)oc * 65536) = o;
    }
  }
}

extern "C" void kernel_launch(void* const* d_in, const int* in_sizes, int n_in,
                              void* d_out, int out_size, void* d_ws, size_t ws_size,
                              hipStream_t stream) {
  const float* x   = (const float*)d_in[0];
  const float* rep = (const float*)d_in[1];
  const float* W   = (const float*)d_in[2];
  float* out = (float*)d_out;
  // grid: b(8) * g(8) * ty(8) * tx(4) = 2048 blocks
  hipLaunchKernelGGL(dynconv_kernel, dim3(2048), dim3(256), 0, stream,
                     x, rep, W, out);
}

// Round 4
// 247.032 us; speedup vs baseline: 1.0159x; 1.0159x over previous
//
#include <hip/hip_runtime.h>

// Dynamic grouped conv, factorized: the dynamic 3x3 kernel is broadcast across
// the 8 input channels of each group, so
//   out[b,oc] = conv3x3( S[b,g], w[b,oc] ),  S[b,g] = sum of the group's 8 chans.
//
// Two-kernel streaming split (S staged in d_ws):
//   A: S = group-sum, pure float4 streaming (134 MB R + 16.8 MB W)
//   B: per-(b,g,16x64 tile): dynamic weights -> LDS tile of S -> 3x3 conv,
//      float4 stores (16.8 MB R + 134 MB W).
//   R4 fix: B's staging needs 288 interior + 36 halo work items but the block
//   has 256 threads -> interior is now a strided loop, halo moved to tid<36.
// Fallback: R2's fused single kernel (verified pass) if ws_size is too small.

#define LDSW 68   // row stride in floats; rows 16B-aligned

__device__ __forceinline__ int reflect1(int i, int n) {
  if (i < 0) i = -i;
  if (i >= n) i = 2 * n - 2 - i;
  return i;
}

// ---------------- Kernel A: group-sum ----------------
__global__ __launch_bounds__(256) void gsum_kernel(
    const float* __restrict__ x,   // [8,64,256,256]
    float* __restrict__ S) {       // [8,8,256,256]
  const int i = blockIdx.x * 256 + threadIdx.x;   // 0 .. 64*16384-1 (float4 idx)
  const int plane = i >> 14;                      // b*8 + g
  const int off = i & 16383;
  const float4* p = (const float4*)x + (size_t)plane * 8 * 16384 + off;
  float4 a;
  {
    float4 v0 = p[0],         v1 = p[16384],     v2 = p[2 * 16384], v3 = p[3 * 16384];
    float4 v4 = p[4 * 16384], v5 = p[5 * 16384], v6 = p[6 * 16384], v7 = p[7 * 16384];
    a.x = ((v0.x + v1.x) + (v2.x + v3.x)) + ((v4.x + v5.x) + (v6.x + v7.x));
    a.y = ((v0.y + v1.y) + (v2.y + v3.y)) + ((v4.y + v5.y) + (v6.y + v7.y));
    a.z = ((v0.z + v1.z) + (v2.z + v3.z)) + ((v4.z + v5.z) + (v6.z + v7.z));
    a.w = ((v0.w + v1.w) + (v2.w + v3.w)) + ((v4.w + v5.w) + (v6.w + v7.w));
  }
  ((float4*)S)[i] = a;
}

// ---------------- Kernel B: dynamic 3x3 conv on S ----------------
// block = (b, g, 16x64 tile); grid = 8*8*16*4 = 4096
#define BTH 16
__global__ __launch_bounds__(256) void dynconv3_kernel(
    const float* __restrict__ S,     // [8,8,256,256]
    const float* __restrict__ rep,   // [8,32]
    const float* __restrict__ W,     // [576,32]
    float* __restrict__ out) {       // [8,64,256,256]
  const int tid = threadIdx.x;
  const int tx = blockIdx.x & 3;           // 4 tiles of 64 along x
  const int ty = (blockIdx.x >> 2) & 15;   // 16 tiles of 16 along y
  const int g  = (blockIdx.x >> 6) & 7;
  const int b  = blockIdx.x >> 9;

  __shared__ float s[(BTH + 2) * LDSW];
  __shared__ float wl[72];

  // dynamic weights for this (b, g)
  if (tid < 72) {
    const int row = g * 72 + tid;          // (g*8 + oc)*9 + tap
    const float* wr = W + (size_t)row * 32;
    const float* rb = rep + b * 32;
    float acc = 0.f;
#pragma unroll
    for (int j = 0; j < 32; ++j) acc += rb[j] * wr[j];
    wl[tid] = (acc > 0.f) ? acc : 0.1f * acc;
  }

  // stage S tile: interior 18 rows x 16 float4 segs (288 items, strided loop);
  // halo cols at s[.,64] (right) / s[.,66] (left), 36 items.
  const int gx0 = tx * 64, gy0 = ty * BTH;
  const float* Sp = S + (size_t)(b * 8 + g) * 65536;
  const float4* Sp4 = (const float4*)Sp;

  for (int t = tid; t < 18 * 16; t += 256) {
    const int row = t >> 4, seg = t & 15;
    const int yy = reflect1(gy0 + row - 1, 256);
    float4 v = Sp4[(size_t)yy * 64 + (gx0 >> 2) + seg];
    *(float4*)&s[row * LDSW + seg * 4] = v;
  }
  if (tid < 36) {
    const int row = tid >> 1, side = tid & 1;
    const int scol = side ? 64 : 66;       // right halo -> col 64, left -> col 66
    const int yy = reflect1(gy0 + row - 1, 256);
    const int xx = reflect1(gx0 + (side ? 64 : -1), 256);
    s[row * LDSW + scol] = Sp[(size_t)yy * 256 + xx];
  }
  __syncthreads();

  // compute: 4 pixels/thread, one pass; window cols cs-1 .. cs+4
  const int cs = (tid & 15) * 4;
  const int rr = tid >> 4;                 // 0..15

  float win[3][6];
#pragma unroll
  for (int dy = 0; dy < 3; ++dy) {
    const float* row = &s[(rr + dy) * LDSW];
    float4 a = *(const float4*)&row[cs];           // cols cs..cs+3 (16B aligned)
    float  r = row[cs + 4];                        // col cs+4 (cs=60 -> halo col 64)
    float  l = row[(cs == 0) ? 66 : cs - 1];       // col cs-1 (cs=0 -> halo col 66)
    win[dy][0] = l;   win[dy][1] = a.x; win[dy][2] = a.y;
    win[dy][3] = a.z; win[dy][4] = a.w; win[dy][5] = r;
  }

  const int y = gy0 + rr;
  float* ob = out + (((size_t)(b * 64 + g * 8) * 256 + y) * 256 + gx0 + cs);

#pragma unroll
  for (int oc = 0; oc < 8; ++oc) {
    const float* w = &wl[oc * 9];
    const float w00 = w[0], w01 = w[1], w02 = w[2];
    const float w10 = w[3], w11 = w[4], w12 = w[5];
    const float w20 = w[6], w21 = w[7], w22 = w[8];
    float4 o;
    o.x = w00 * win[0][0] + w01 * win[0][1] + w02 * win[0][2]
        + w10 * win[1][0] + w11 * win[1][1] + w12 * win[1][2]
        + w20 * win[2][0] + w21 * win[2][1] + w22 * win[2][2];
    o.y = w00 * win[0][1] + w01 * win[0][2] + w02 * win[0][3]
        + w10 * win[1][1] + w11 * win[1][2] + w12 * win[1][3]
        + w20 * win[2][1] + w21 * win[2][2] + w22 * win[2][3];
    o.z = w00 * win[0][2] + w01 * win[0][3] + w02 * win[0][4]
        + w10 * win[1][2] + w11 * win[1][3] + w12 * win[1][4]
        + w20 * win[2][2] + w21 * win[2][3] + w22 * win[2][4];
    o.w = w00 * win[0][3] + w01 * win[0][4] + w02 * win[0][5]
        + w10 * win[1][3] + w11 * win[1][4] + w12 * win[1][5]
        + w20 * win[2][3] + w21 * win[2][4] + w22 * win[2][5];
    *(float4*)(ob + (size_t)oc * 65536) = o;
  }
}

// ---------------- Fallback: R2 fused kernel (verified pass) ----------------
#define TH 32
#define TW 64
__global__ __launch_bounds__(256) void dynconv_fused_kernel(
    const float* __restrict__ x, const float* __restrict__ rep,
    const float* __restrict__ W, float* __restrict__ out) {
  const int tid = threadIdx.x;
  const int tx = blockIdx.x & 3;
  const int ty = (blockIdx.x >> 2) & 7;
  const int g  = (blockIdx.x >> 5) & 7;
  const int b  = blockIdx.x >> 8;

  __shared__ float s[(TH + 2) * LDSW];
  __shared__ float wl[72];

  if (tid < 72) {
    const int row = g * 72 + tid;
    const float* wr = W + (size_t)row * 32;
    const float* rb = rep + b * 32;
    float acc = 0.f;
#pragma unroll
    for (int j = 0; j < 32; ++j) acc += rb[j] * wr[j];
    wl[tid] = (acc > 0.f) ? acc : 0.1f * acc;
  }
  __syncthreads();

  const int gx0 = tx * TW, gy0 = ty * TH;
  const float* xg = x + ((size_t)(b * 64 + g * 8)) * 65536;
  const float4* xg4 = (const float4*)xg;

  for (int t = tid; t < 34 * 16; t += 256) {
    const int row = t >> 4, seg = t & 15;
    const int yy = reflect1(gy0 + row - 1, 256);
    const float4* p = xg4 + (size_t)yy * 64 + (gx0 >> 2) + seg;
    float4 a; a.x = 0.f; a.y = 0.f; a.z = 0.f; a.w = 0.f;
#pragma unroll
    for (int c = 0; c < 8; ++c) {
      float4 v = p[(size_t)c * 16384];
      a.x += v.x; a.y += v.y; a.z += v.z; a.w += v.w;
    }
    *(float4*)&s[row * LDSW + seg * 4] = a;
  }
  if (tid < 68) {
    const int row = tid >> 1, side = tid & 1;
    const int scol = side ? 64 : 66;
    const int yy = reflect1(gy0 + row - 1, 256);
    const int xx = reflect1(gx0 + (side ? 64 : -1), 256);
    const float* p = xg + (size_t)yy * 256 + xx;
    float a = 0.f;
#pragma unroll
    for (int c = 0; c < 8; ++c) a += p[(size_t)c * 65536];
    s[row * LDSW + scol] = a;
  }
  __syncthreads();

  const int cs = (tid & 15) * 4;
  const int r0 = tid >> 4;
  for (int rr = r0; rr < TH; rr += 16) {
    float win[3][6];
#pragma unroll
    for (int dy = 0; dy < 3; ++dy) {
      const float* row = &s[(rr + dy) * LDSW];
      float4 a = *(const float4*)&row[cs];
      float  r = row[cs + 4];
      float  l = row[(cs == 0) ? 66 : cs - 1];
      win[dy][0] = l;   win[dy][1] = a.x; win[dy][2] = a.y;
      win[dy][3] = a.z; win[dy][4] = a.w; win[dy][5] = r;
    }
    const int y = gy0 + rr;
    float* ob = out + (((size_t)(b * 64 + g * 8) * 256 + y) * 256 + gx0 + cs);
#pragma unroll
    for (int oc = 0; oc < 8; ++oc) {
      const float* w = &wl[oc * 9];
      const float w00 = w[0], w01 = w[1], w02 = w[2];
      const float w10 = w[3], w11 = w[4], w12 = w[5];
      const float w20 = w[6], w21 = w[7], w22 = w[8];
      float4 o;
      o.x = w00 * win[0][0] + w01 * win[0][1] + w02 * win[0][2]
          + w10 * win[1][0] + w11 * win[1][1] + w12 * win[1][2]
          + w20 * win[2][0] + w21 * win[2][1] + w22 * win[2][2];
      o.y = w00 * win[0][1] + w01 * win[0][2] + w02 * win[0][3]
          + w10 * win[1][1] + w11 * win[1][2] + w12 * win[1][3]
          + w20 * win[2][1] + w21 * win[2][2] + w22 * win[2][3];
      o.z = w00 * win[0][2] + w01 * win[0][3] + w02 * win[0][4]
          + w10 * win[1][2] + w11 * win[1][3] + w12 * win[1][4]
          + w20 * win[2][2] + w21 * win[2][3] + w22 * win[2][4];
      o.w = w00 * win[0][3] + w01 * win[0][4] + w02 * win[0][5]
          + w10 * win[1][3] + w11 * win[1][4] + w12 * win[1][5]
          + w20 * win[2][3] + w21 * win[2][4] + w22 * win[2][5];
      *(float4*)(ob + (size_t)oc * 65536) = o;
    }
  }
}

extern "C" void kernel_launch(void* const* d_in, const int* in_sizes, int n_in,
                              void* d_out, int out_size, void* d_ws, size_t ws_size,
                              hipStream_t stream) {
  const float* x   = (const float*)d_in[0];
  const float* rep = (const float*)d_in[1];
  const float* W   = (const float*)d_in[2];
  float* out = (float*)d_out;

  const size_t s_bytes = (size_t)8 * 8 * 256 * 256 * sizeof(float);  // 16.78 MB
  if (ws_size >= s_bytes) {
    float* S = (float*)d_ws;
    hipLaunchKernelGGL(gsum_kernel, dim3(4096), dim3(256), 0, stream, x, S);
    hipLaunchKernelGGL(dynconv3_kernel, dim3(4096), dim3(256), 0, stream,
                       S, rep, W, out);
  } else {
    hipLaunchKernelGGL(dynconv_fused_kernel, dim3(2048), dim3(256), 0, stream,
                       x, rep, W, out);
  }
}